// Round 4
// baseline (224.870 us; speedup 1.0000x reference)
//
#include <hip/hip_runtime.h>
#include <stdint.h>

// QuantizedConv2d int8 implicit GEMM via MFMA i32_16x16x64_i8.
// N=32, C_in=128, H=W=56, C_out=256, 3x3, pad 1, stride 1.
// Output int8 values stored as int32 (harness reads integer outputs as np.int32).
//
// R14: LDS-bandwidth rework. R13 was LDS-read bound: 1 MFMA per ds_read_b128
// (and 4 waves/block reading identical A addresses) -> ~35 us of LDS traffic
// per CU vs 15 us of MFMA. Changes:
//  - Wave = 7 mt x 2 ct (112 M x 32 co): each a0/a1 LDS pair feeds 4 MFMAs
//    (ratio 2x vs R13). Block = 4 waves = 112 M x 128 co.
//  - 1792 tiles = 32 n x 28 slabs x 2 co128 on 512 blocks: i<32 -> 4 tiles,
//    i>=32 -> 3 tiles; each CU gets one of each = 7 tile-periods, balanced.
//  - breg = 36 v4i pinned via asm value-opacity (R12's VGPR=168 showed
//    invariant bp loads rematerialize into the loop through fences; opaque
//    asm results cannot).
//  - Async A dbuf unchanged: 8 global_load_lds before K-loop, counted
//    s_waitcnt vmcnt(14) (this tile's 14 stores stay in flight) + raw
//    s_barrier. No vmcnt(0) in the loop. s_setprio(1) around the K-loop.

#define NB 32
#define CI 128
#define HH 56
#define WW 56
#define CO 256
#define SPA (HH * WW)              // 3136 = 28 slabs x 112 (2 image rows each)
#define HP 58
#define WP 64
#define XP2_BYTES (NB * HP * WP * CI)      // 15204352
#define BP_BYTES (9 * 2 * 4 * CO * 16)     // 294912
#define ABUF (4 * 8192)                    // 4 padded rows = 32 KB

typedef int v4i __attribute__((ext_vector_type(4)));

// ---- prep (unchanged from R10) ----
// [0,1792): pack one (n,h) row -> padded NHWC int8, pad byte = zp, XOR-swizzled
// [1792,1856): border h-rows = zp
// [1856,2112): weight pack + BG[co] = bias - zp*S9
__global__ __launch_bounds__(256) void prep_kernel(
    const int* __restrict__ x, const int* __restrict__ wgt,
    const int* __restrict__ bias, const int* __restrict__ zpi,
    int8_t* __restrict__ xp2, int8_t* __restrict__ bp, int* __restrict__ BG)
{
    __shared__ int sm[1824];
    const int tid = threadIdx.x, bid = blockIdx.x;
    const int zp = *zpi;
    const int zp4 = (zp & 255) * 0x01010101;

    if (bid < HH * NB) {
        const int n = bid / HH, h = bid % HH;
        #pragma unroll
        for (int it = 0; it < 7; ++it) {
            int j = tid + it * 256;                 // 1792 = 128 ci x 14 w4
            int ci = j / 14, w4 = j - ci * 14;
            const v4i v = *(const v4i*)(x + ((n * CI + ci) * HH + h) * WW + w4 * 4);
            sm[w4 * 130 + ci] = (v.x & 255) | ((v.y & 255) << 8) |
                                ((v.z & 255) << 16) | (v.w << 24);
        }
        __syncthreads();
        int* od = (int*)xp2 + (n * HP + h + 1) * (WP * CI / 4);  // 2048 dwords
        #pragma unroll
        for (int it = 0; it < 8; ++it) {
            int j = tid + it * 256;                 // j = widx*32 + ci4
            int widx = j >> 5, ci4 = j & 31;
            int val = zp4;                          // pad value = zp
            if (widx >= 1 && widx <= WW) {
                int w = widx - 1;
                int base = (w >> 2) * 130 + ci4 * 4;
                int sh = (w & 3) * 8;
                val = ((sm[base] >> sh) & 0xff) | (((sm[base+1] >> sh) & 0xff) << 8) |
                      (((sm[base+2] >> sh) & 0xff) << 16) | ((sm[base+3] >> sh) << 24);
            }
            od[j ^ ((widx & 7) << 2)] = val;        // XOR-swizzle 16-B units
        }
    } else if (bid < HH * NB + 2 * NB) {
        const int z = bid - HH * NB;
        const int n = z >> 1, hidx = (z & 1) ? (HP - 1) : 0;
        int* od = (int*)xp2 + (n * HP + hidx) * (WP * CI / 4);
        #pragma unroll
        for (int it = 0; it < 8; ++it) od[tid + it * 256] = zp4;  // zp border rows
    } else {
        const int co = bid - (HH * NB + 2 * NB);
        for (int j = tid; j < 1152; j += 256) sm[j] = wgt[co * 1152 + j];  // [ci][9]
        __syncthreads();
        for (int j = tid; j < 288; j += 256) {      // 9t x 2c64 x 4q x 4j4
            int j4 = j & 3, q = (j >> 2) & 3, c64 = (j >> 4) & 1, t = j >> 5;
            int ci = c64 * 64 + q * 16 + j4 * 4;
            int b0 = sm[(ci + 0) * 9 + t] & 255, b1 = sm[(ci + 1) * 9 + t] & 255;
            int b2 = sm[(ci + 2) * 9 + t] & 255, b3 = sm[(ci + 3) * 9 + t];
            ((int*)bp)[((t * 2 + c64) * 4 + q) * 1024 + co * 4 + j4] =
                b0 | (b1 << 8) | (b2 << 16) | (b3 << 24);
        }
        if (tid < 9) {
            int s = 0;
            for (int ci = 0; ci < CI; ++ci) s += sm[ci * 9 + tid];
            sm[1152 + tid] = s;
        }
        __syncthreads();
        if (tid == 0) {
            int s9 = 0;
            for (int t = 0; t < 9; ++t) s9 += sm[1152 + t];
            BG[co] = bias[co] - zp * s9;            // cls-independent correction
        }
    }
}

// ---- main: 512 blocks x 256 thr, 2 blocks/CU; block = 112M x 128co ----
__global__ __launch_bounds__(256, 2) void qconv_mfma(
    const int8_t* __restrict__ xp2, const int8_t* __restrict__ bp,
    const int* __restrict__ BG,
    const float* __restrict__ si, const float* __restrict__ sw,
    const float* __restrict__ so, const int* __restrict__ zpo,
    int* __restrict__ out)
{
    const int tid  = threadIdx.x, lane = tid & 63, wid = tid >> 6;
    const int quad = lane >> 4, lo16 = lane & 15;
    const int bid  = blockIdx.x;                    // 512 blocks, 2 per CU
    const int xcd  = bid & 7, i = bid >> 3;         // i 0..63 within XCD
    // tiles per XCD: 224 = 4n x 2cb x 28s; this block's tiles t_j = i + 64*j
    const int n    = xcd * 4 + (i & 3);             // constant across j
    const int cb   = (i >> 2) & 1;                  // constant across j
    const int sA   = i >> 3;                        // s_j = sA + 8*j
    const int ntiles = (i < 32) ? 4 : 3;
    const int cw   = cb * 128 + wid * 32;           // wave co base (32 co)

    __shared__ __attribute__((aligned(16))) int8_t Asm[2][ABUF];  // 64 KB

    // ---- prologue: stage slab sA (4 padded rows, 32 KB) into buf0 ----
    const int8_t* src0 = xp2 + (((size_t)n * HP + 2 * sA) << 13);
    #pragma unroll
    for (int k = 0; k < 8; ++k) {
        const int u = wid + 4 * k;                  // 32 x 1-KB units
        __builtin_amdgcn_global_load_lds(
            (const __attribute__((address_space(1))) void*)(src0 + (u << 10) + lane * 16),
            (__attribute__((address_space(3))) void*)(&Asm[0][u << 10]), 16, 0, 0);
    }

    // ---- B -> registers: breg[tap][c64][ct], 36 v4i, pinned opaque ----
    v4i breg[9][2][2];
    #pragma unroll
    for (int t = 0; t < 9; ++t)
        #pragma unroll
        for (int c = 0; c < 2; ++c)
            #pragma unroll
            for (int ct = 0; ct < 2; ++ct) {
                breg[t][c][ct] = *(const v4i*)(bp + (((t * 2 + c) * 4 + quad) << 12) +
                                               ((cw + ct * 16 + lo16) << 4));
                // value-opacity: invariant load cannot rematerialize in-loop
                asm volatile("" : "+v"(breg[t][c][ct]));
            }

    int bgv[2];
    #pragma unroll
    for (int ct = 0; ct < 2; ++ct) bgv[ct] = BG[cw + ct * 16 + lo16];
    const float rs = (*si) * (*sw) / (*so);
    const float zo = (float)(*zpo);

    // per-mt geometry (slab-local): base offset + packed swizzle per tap-col
    int boff[7], sw3[7];
    #pragma unroll
    for (int mt = 0; mt < 7; ++mt) {
        const int ml = mt * 16 + lo16;              // 0..111 within slab
        const int srow = ml / 56, scol = ml - srow * 56;
        boff[mt] = srow * 8192 + scol * 128 + quad * 16;
        int s0 = ((scol + 0) & 7) << 4, s1 = ((scol + 1) & 7) << 4,
            s2 = ((scol + 2) & 7) << 4;
        sw3[mt] = s0 | (s1 << 8) | (s2 << 16);      // swizzle per dc, packed
    }

    int* optr0 = out + ((size_t)n * CO + cw + lo16) * SPA + quad * 4;
    int* optr1 = optr0 + 16 * SPA;

    __syncthreads();                                // prologue drained (vmcnt(0) ok here)

    #pragma unroll 1
    for (int j = 0; j < ntiles; ++j) {
        const int s = sA + 8 * j;                   // slab 0..27
        const int8_t* curA = Asm[j & 1];

        // ---- issue async stage of slab s+8 into the idle buffer ----
        if (j + 1 < ntiles) {
            const int8_t* srcn = xp2 + (((size_t)n * HP + 2 * (s + 8)) << 13);
            int8_t* dst = (int8_t*)Asm[(j & 1) ^ 1];
            #pragma unroll
            for (int k = 0; k < 8; ++k) {
                const int u = wid + 4 * k;
                __builtin_amdgcn_global_load_lds(
                    (const __attribute__((address_space(1))) void*)(srcn + (u << 10) + lane * 16),
                    (__attribute__((address_space(3))) void*)(dst + (u << 10)), 16, 0, 0);
            }
        }
        __builtin_amdgcn_sched_barrier(0);          // pin load issue before K-loop

        v4i acc[7][2];
        #pragma unroll
        for (int mt = 0; mt < 7; ++mt) {
            acc[mt][0] = (v4i){0, 0, 0, 0};
            acc[mt][1] = (v4i){0, 0, 0, 0};
        }

        // ---- K-loop: 9 taps x 7 mt x (2 reads + 4 MFMA) ----
        __builtin_amdgcn_s_setprio(1);
        #pragma unroll
        for (int tp = 0; tp < 9; ++tp) {
            const int dr = tp / 3, dc = tp % 3;
            #pragma unroll
            for (int mt = 0; mt < 7; ++mt) {
                const int off  = boff[mt] + dr * 8192 + dc * 128;
                const int phys = off ^ ((sw3[mt] >> (8 * dc)) & 0x70);
                v4i a0 = *(const v4i*)(curA + phys);          // logical ci 0..63
                v4i a1 = *(const v4i*)(curA + (phys ^ 64));   // logical +64 -> phys^64
                acc[mt][0] = __builtin_amdgcn_mfma_i32_16x16x64_i8(a0, breg[tp][0][0], acc[mt][0], 0, 0, 0);
                acc[mt][1] = __builtin_amdgcn_mfma_i32_16x16x64_i8(a0, breg[tp][0][1], acc[mt][1], 0, 0, 0);
                acc[mt][0] = __builtin_amdgcn_mfma_i32_16x16x64_i8(a1, breg[tp][1][0], acc[mt][0], 0, 0, 0);
                acc[mt][1] = __builtin_amdgcn_mfma_i32_16x16x64_i8(a1, breg[tp][1][1], acc[mt][1], 0, 0, 0);
            }
        }
        __builtin_amdgcn_s_setprio(0);

        // ---- epilogue: requant + 14 direct v4i stores (after the 8 loads) ----
        const int m0 = s * 112;
        #pragma unroll
        for (int mt = 0; mt < 7; ++mt) {
            v4i v0, v1;
            #pragma unroll
            for (int i4 = 0; i4 < 4; ++i4) {        // C/D row = quad*4+i4
                float y0 = rintf((float)(acc[mt][0][i4] + bgv[0]) * rs + zo);
                float y1 = rintf((float)(acc[mt][1][i4] + bgv[1]) * rs + zo);
                v0[i4] = (int)fminf(fmaxf(y0, -128.f), 127.f);
                v1[i4] = (int)fminf(fmaxf(y1, -128.f), 127.f);
            }
            *(v4i*)(optr0 + m0 + mt * 16) = v0;
            *(v4i*)(optr1 + m0 + mt * 16) = v1;
        }

        // ---- release: wait only for the 8 stage loads (14 newest = stores
        //      stay in flight), then barrier. No vmcnt(0) in the loop. ----
        if (j + 1 < ntiles) {
            __builtin_amdgcn_sched_barrier(0);
            asm volatile("s_waitcnt vmcnt(14)" ::: "memory");
            __builtin_amdgcn_s_barrier();
            __builtin_amdgcn_sched_barrier(0);
        }
    }
}

extern "C" void kernel_launch(void* const* d_in, const int* in_sizes, int n_in,
                              void* d_out, int out_size, void* d_ws, size_t ws_size,
                              hipStream_t stream) {
    const int*   x    = (const int*)d_in[0];
    const int*   wgt  = (const int*)d_in[1];
    const int*   bias = (const int*)d_in[2];
    const float* si   = (const float*)d_in[3];
    const float* sw   = (const float*)d_in[4];
    const float* so   = (const float*)d_in[5];
    const int*   zpi  = (const int*)d_in[6];
    const int*   zpo  = (const int*)d_in[7];
    int* out = (int*)d_out;

    int8_t* xp2 = (int8_t*)d_ws;
    int8_t* bp  = xp2 + XP2_BYTES;
    int*    bg  = (int*)(bp + BP_BYTES);

    prep_kernel<<<HH * NB + 2 * NB + CO, 256, 0, stream>>>(x, wgt, bias, zpi, xp2, bp, bg);
    qconv_mfma<<<512, 256, 0, stream>>>(xp2, bp, bg, si, sw, so, zpo, out);
}

// Round 5
// 224.229 us; speedup vs baseline: 1.0029x; 1.0029x over previous
//
#include <hip/hip_runtime.h>
#include <stdint.h>

// QuantizedConv2d int8 implicit GEMM via MFMA i32_16x16x64_i8.
// N=32, C_in=128, H=W=56, C_out=256, 3x3, pad 1, stride 1.
// Output int8 values stored as int32 (harness reads integer outputs as np.int32).
//
// R15 = R14 with the register allocation fixed. R14's VGPR_Count=128 proved
// the allocator targeted 4 waves/EU (launch_bounds' 2nd arg is only a MINIMUM)
// and spilled the pinned 144-reg B panel to scratch: FETCH_SIZE 8.9->55.4 MB,
// WRITE 103->132 MB, qconv 59->86 us. amdgpu_waves_per_eu(2,2) pins the
// occupancy target to exactly 2 waves/EU -> 256-VGPR budget -> the ~245-reg
// plan fits with zero spill. Structure otherwise identical to R14:
//  - Wave = 7 mt x 2 ct (112 M x 32 co): each a0/a1 LDS pair feeds 4 MFMAs.
//  - 1792 tiles = 32 n x 28 slabs x 2 co128 on 512 blocks (2/CU); i<32 -> 4
//    tiles, i>=32 -> 3; each CU hosts one of each = 7 balanced tile-periods.
//  - breg = 36 v4i pinned opaque (no remat); async A dbuf via global_load_lds
//    + counted s_waitcnt vmcnt(14) + raw s_barrier; no vmcnt(0) in the loop.

#define NB 32
#define CI 128
#define HH 56
#define WW 56
#define CO 256
#define SPA (HH * WW)              // 3136 = 28 slabs x 112 (2 image rows each)
#define HP 58
#define WP 64
#define XP2_BYTES (NB * HP * WP * CI)      // 15204352
#define BP_BYTES (9 * 2 * 4 * CO * 16)     // 294912
#define ABUF (4 * 8192)                    // 4 padded rows = 32 KB

typedef int v4i __attribute__((ext_vector_type(4)));

// ---- prep (unchanged from R10) ----
// [0,1792): pack one (n,h) row -> padded NHWC int8, pad byte = zp, XOR-swizzled
// [1792,1856): border h-rows = zp
// [1856,2112): weight pack + BG[co] = bias - zp*S9
__global__ __launch_bounds__(256) void prep_kernel(
    const int* __restrict__ x, const int* __restrict__ wgt,
    const int* __restrict__ bias, const int* __restrict__ zpi,
    int8_t* __restrict__ xp2, int8_t* __restrict__ bp, int* __restrict__ BG)
{
    __shared__ int sm[1824];
    const int tid = threadIdx.x, bid = blockIdx.x;
    const int zp = *zpi;
    const int zp4 = (zp & 255) * 0x01010101;

    if (bid < HH * NB) {
        const int n = bid / HH, h = bid % HH;
        #pragma unroll
        for (int it = 0; it < 7; ++it) {
            int j = tid + it * 256;                 // 1792 = 128 ci x 14 w4
            int ci = j / 14, w4 = j - ci * 14;
            const v4i v = *(const v4i*)(x + ((n * CI + ci) * HH + h) * WW + w4 * 4);
            sm[w4 * 130 + ci] = (v.x & 255) | ((v.y & 255) << 8) |
                                ((v.z & 255) << 16) | (v.w << 24);
        }
        __syncthreads();
        int* od = (int*)xp2 + (n * HP + h + 1) * (WP * CI / 4);  // 2048 dwords
        #pragma unroll
        for (int it = 0; it < 8; ++it) {
            int j = tid + it * 256;                 // j = widx*32 + ci4
            int widx = j >> 5, ci4 = j & 31;
            int val = zp4;                          // pad value = zp
            if (widx >= 1 && widx <= WW) {
                int w = widx - 1;
                int base = (w >> 2) * 130 + ci4 * 4;
                int sh = (w & 3) * 8;
                val = ((sm[base] >> sh) & 0xff) | (((sm[base+1] >> sh) & 0xff) << 8) |
                      (((sm[base+2] >> sh) & 0xff) << 16) | ((sm[base+3] >> sh) << 24);
            }
            od[j ^ ((widx & 7) << 2)] = val;        // XOR-swizzle 16-B units
        }
    } else if (bid < HH * NB + 2 * NB) {
        const int z = bid - HH * NB;
        const int n = z >> 1, hidx = (z & 1) ? (HP - 1) : 0;
        int* od = (int*)xp2 + (n * HP + hidx) * (WP * CI / 4);
        #pragma unroll
        for (int it = 0; it < 8; ++it) od[tid + it * 256] = zp4;  // zp border rows
    } else {
        const int co = bid - (HH * NB + 2 * NB);
        for (int j = tid; j < 1152; j += 256) sm[j] = wgt[co * 1152 + j];  // [ci][9]
        __syncthreads();
        for (int j = tid; j < 288; j += 256) {      // 9t x 2c64 x 4q x 4j4
            int j4 = j & 3, q = (j >> 2) & 3, c64 = (j >> 4) & 1, t = j >> 5;
            int ci = c64 * 64 + q * 16 + j4 * 4;
            int b0 = sm[(ci + 0) * 9 + t] & 255, b1 = sm[(ci + 1) * 9 + t] & 255;
            int b2 = sm[(ci + 2) * 9 + t] & 255, b3 = sm[(ci + 3) * 9 + t];
            ((int*)bp)[((t * 2 + c64) * 4 + q) * 1024 + co * 4 + j4] =
                b0 | (b1 << 8) | (b2 << 16) | (b3 << 24);
        }
        if (tid < 9) {
            int s = 0;
            for (int ci = 0; ci < CI; ++ci) s += sm[ci * 9 + tid];
            sm[1152 + tid] = s;
        }
        __syncthreads();
        if (tid == 0) {
            int s9 = 0;
            for (int t = 0; t < 9; ++t) s9 += sm[1152 + t];
            BG[co] = bias[co] - zp * s9;            // cls-independent correction
        }
    }
}

// ---- main: 512 blocks x 256 thr, exactly 2 waves/EU; block = 112M x 128co ----
__global__ __launch_bounds__(256)
__attribute__((amdgpu_waves_per_eu(2, 2)))          // pin allocator target: 256-VGPR budget
void qconv_mfma(
    const int8_t* __restrict__ xp2, const int8_t* __restrict__ bp,
    const int* __restrict__ BG,
    const float* __restrict__ si, const float* __restrict__ sw,
    const float* __restrict__ so, const int* __restrict__ zpo,
    int* __restrict__ out)
{
    const int tid  = threadIdx.x, lane = tid & 63, wid = tid >> 6;
    const int quad = lane >> 4, lo16 = lane & 15;
    const int bid  = blockIdx.x;                    // 512 blocks, 2 per CU
    const int xcd  = bid & 7, i = bid >> 3;         // i 0..63 within XCD
    // tiles per XCD: 224 = 4n x 2cb x 28s; this block's tiles t_j = i + 64*j
    const int n    = xcd * 4 + (i & 3);             // constant across j
    const int cb   = (i >> 2) & 1;                  // constant across j
    const int sA   = i >> 3;                        // s_j = sA + 8*j
    const int ntiles = (i < 32) ? 4 : 3;
    const int cw   = cb * 128 + wid * 32;           // wave co base (32 co)

    __shared__ __attribute__((aligned(16))) int8_t Asm[2][ABUF];  // 64 KB

    // ---- prologue: stage slab sA (4 padded rows, 32 KB) into buf0 ----
    const int8_t* src0 = xp2 + (((size_t)n * HP + 2 * sA) << 13);
    #pragma unroll
    for (int k = 0; k < 8; ++k) {
        const int u = wid + 4 * k;                  // 32 x 1-KB units
        __builtin_amdgcn_global_load_lds(
            (const __attribute__((address_space(1))) void*)(src0 + (u << 10) + lane * 16),
            (__attribute__((address_space(3))) void*)(&Asm[0][u << 10]), 16, 0, 0);
    }

    // ---- B -> registers: breg[tap][c64][ct], 36 v4i, pinned opaque ----
    v4i breg[9][2][2];
    #pragma unroll
    for (int t = 0; t < 9; ++t)
        #pragma unroll
        for (int c = 0; c < 2; ++c)
            #pragma unroll
            for (int ct = 0; ct < 2; ++ct) {
                breg[t][c][ct] = *(const v4i*)(bp + (((t * 2 + c) * 4 + quad) << 12) +
                                               ((cw + ct * 16 + lo16) << 4));
                // value-opacity: invariant load cannot rematerialize in-loop
                asm volatile("" : "+v"(breg[t][c][ct]));
            }

    int bgv[2];
    #pragma unroll
    for (int ct = 0; ct < 2; ++ct) bgv[ct] = BG[cw + ct * 16 + lo16];
    const float rs = (*si) * (*sw) / (*so);
    const float zo = (float)(*zpo);

    // per-mt geometry (slab-local): base offset + packed swizzle per tap-col
    int boff[7], sw3[7];
    #pragma unroll
    for (int mt = 0; mt < 7; ++mt) {
        const int ml = mt * 16 + lo16;              // 0..111 within slab
        const int srow = ml / 56, scol = ml - srow * 56;
        boff[mt] = srow * 8192 + scol * 128 + quad * 16;
        int s0 = ((scol + 0) & 7) << 4, s1 = ((scol + 1) & 7) << 4,
            s2 = ((scol + 2) & 7) << 4;
        sw3[mt] = s0 | (s1 << 8) | (s2 << 16);      // swizzle per dc, packed
    }

    int* optr0 = out + ((size_t)n * CO + cw + lo16) * SPA + quad * 4;
    int* optr1 = optr0 + 16 * SPA;

    __syncthreads();                                // prologue drained (vmcnt(0) ok here)

    #pragma unroll 1
    for (int j = 0; j < ntiles; ++j) {
        const int s = sA + 8 * j;                   // slab 0..27
        const int8_t* curA = Asm[j & 1];

        // ---- issue async stage of slab s+8 into the idle buffer ----
        if (j + 1 < ntiles) {
            const int8_t* srcn = xp2 + (((size_t)n * HP + 2 * (s + 8)) << 13);
            int8_t* dst = (int8_t*)Asm[(j & 1) ^ 1];
            #pragma unroll
            for (int k = 0; k < 8; ++k) {
                const int u = wid + 4 * k;
                __builtin_amdgcn_global_load_lds(
                    (const __attribute__((address_space(1))) void*)(srcn + (u << 10) + lane * 16),
                    (__attribute__((address_space(3))) void*)(dst + (u << 10)), 16, 0, 0);
            }
        }
        __builtin_amdgcn_sched_barrier(0);          // pin load issue before K-loop

        v4i acc[7][2];
        #pragma unroll
        for (int mt = 0; mt < 7; ++mt) {
            acc[mt][0] = (v4i){0, 0, 0, 0};
            acc[mt][1] = (v4i){0, 0, 0, 0};
        }

        // ---- K-loop: 9 taps x 7 mt x (2 reads + 4 MFMA) ----
        __builtin_amdgcn_s_setprio(1);
        #pragma unroll
        for (int tp = 0; tp < 9; ++tp) {
            const int dr = tp / 3, dc = tp % 3;
            #pragma unroll
            for (int mt = 0; mt < 7; ++mt) {
                const int off  = boff[mt] + dr * 8192 + dc * 128;
                const int phys = off ^ ((sw3[mt] >> (8 * dc)) & 0x70);
                v4i a0 = *(const v4i*)(curA + phys);          // logical ci 0..63
                v4i a1 = *(const v4i*)(curA + (phys ^ 64));   // logical +64 -> phys^64
                acc[mt][0] = __builtin_amdgcn_mfma_i32_16x16x64_i8(a0, breg[tp][0][0], acc[mt][0], 0, 0, 0);
                acc[mt][1] = __builtin_amdgcn_mfma_i32_16x16x64_i8(a0, breg[tp][0][1], acc[mt][1], 0, 0, 0);
                acc[mt][0] = __builtin_amdgcn_mfma_i32_16x16x64_i8(a1, breg[tp][1][0], acc[mt][0], 0, 0, 0);
                acc[mt][1] = __builtin_amdgcn_mfma_i32_16x16x64_i8(a1, breg[tp][1][1], acc[mt][1], 0, 0, 0);
            }
        }
        __builtin_amdgcn_s_setprio(0);

        // ---- epilogue: requant + 14 direct v4i stores (after the 8 loads) ----
        const int m0 = s * 112;
        #pragma unroll
        for (int mt = 0; mt < 7; ++mt) {
            v4i v0, v1;
            #pragma unroll
            for (int i4 = 0; i4 < 4; ++i4) {        // C/D row = quad*4+i4
                float y0 = rintf((float)(acc[mt][0][i4] + bgv[0]) * rs + zo);
                float y1 = rintf((float)(acc[mt][1][i4] + bgv[1]) * rs + zo);
                v0[i4] = (int)fminf(fmaxf(y0, -128.f), 127.f);
                v1[i4] = (int)fminf(fmaxf(y1, -128.f), 127.f);
            }
            *(v4i*)(optr0 + m0 + mt * 16) = v0;
            *(v4i*)(optr1 + m0 + mt * 16) = v1;
        }

        // ---- release: wait only for the 8 stage loads (14 newest = stores
        //      stay in flight), then barrier. No vmcnt(0) in the loop. ----
        if (j + 1 < ntiles) {
            __builtin_amdgcn_sched_barrier(0);
            asm volatile("s_waitcnt vmcnt(14)" ::: "memory");
            __builtin_amdgcn_s_barrier();
            __builtin_amdgcn_sched_barrier(0);
        }
    }
}

extern "C" void kernel_launch(void* const* d_in, const int* in_sizes, int n_in,
                              void* d_out, int out_size, void* d_ws, size_t ws_size,
                              hipStream_t stream) {
    const int*   x    = (const int*)d_in[0];
    const int*   wgt  = (const int*)d_in[1];
    const int*   bias = (const int*)d_in[2];
    const float* si   = (const float*)d_in[3];
    const float* sw   = (const float*)d_in[4];
    const float* so   = (const float*)d_in[5];
    const int*   zpi  = (const int*)d_in[6];
    const int*   zpo  = (const int*)d_in[7];
    int* out = (int*)d_out;

    int8_t* xp2 = (int8_t*)d_ws;
    int8_t* bp  = xp2 + XP2_BYTES;
    int*    bg  = (int*)(bp + BP_BYTES);

    prep_kernel<<<HH * NB + 2 * NB + CO, 256, 0, stream>>>(x, wgt, bias, zpi, xp2, bp, bg);
    qconv_mfma<<<512, 256, 0, stream>>>(xp2, bp, bg, si, sw, so, zpo, out);
}

// Round 6
// 187.601 us; speedup vs baseline: 1.1987x; 1.1952x over previous
//
#include <hip/hip_runtime.h>
#include <stdint.h>

// QuantizedConv2d int8 implicit GEMM via MFMA i32_16x16x64_i8.
// N=32, C_in=128, H=W=56, C_out=256, 3x3, pad 1, stride 1.
// Output int8 values stored as int32 (harness reads integer outputs as np.int32).
//
// R16: ratio-2 WITHOUT the 144-reg B panel. R14/R15 proved the allocator
// refuses ~245-reg plans (grants 128, spills acc -> FETCH 8.9->55 MB,
// 86 us). Here B streams from L2 per tap (bp = 288 KB, XCD-L2-resident):
//  - per tap the wave loads 4 x v4i B fragments, issued 2 taps ahead
//    (~600 cyc of MFMA cover the ~200 cyc L2 hit); peak B-live ~12 v4i.
//  - per-tap base pointer laundered via asm volatile inside the tile loop:
//    blocks LICM from hoisting the (tile-invariant) B loads back into a
//    36-v4i panel.
//  - vmcnt ordering: B(tap0),B(tap1) issue BEFORE the A-stage, so early-tap
//    B consumption never drains the async A staging; for tap>=2 the A-stage
//    is complete anyway (in-order waits are then free).
//  - register plan ~165 (acc 56 + B-in-flight ~48 + addressing) -- in the
//    range the allocator demonstrably grants (R12/R13: 168).
// Rest identical to R14: wave = 7 mt x 2 ct (112 M x 32 co), 4 MFMA per
// a0/a1 LDS pair; 1792 tiles = 32 n x 28 slabs x 2 co128 on 512 blocks
// (2/CU, i<32 -> 4 tiles else 3); async A dbuf via global_load_lds +
// counted s_waitcnt vmcnt(14) + raw s_barrier; no vmcnt(0) in the loop.

#define NB 32
#define CI 128
#define HH 56
#define WW 56
#define CO 256
#define SPA (HH * WW)              // 3136 = 28 slabs x 112 (2 image rows each)
#define HP 58
#define WP 64
#define XP2_BYTES (NB * HP * WP * CI)      // 15204352
#define BP_BYTES (9 * 2 * 4 * CO * 16)     // 294912
#define ABUF (4 * 8192)                    // 4 padded rows = 32 KB

typedef int v4i __attribute__((ext_vector_type(4)));

// ---- prep (unchanged from R10) ----
// [0,1792): pack one (n,h) row -> padded NHWC int8, pad byte = zp, XOR-swizzled
// [1792,1856): border h-rows = zp
// [1856,2112): weight pack + BG[co] = bias - zp*S9
__global__ __launch_bounds__(256) void prep_kernel(
    const int* __restrict__ x, const int* __restrict__ wgt,
    const int* __restrict__ bias, const int* __restrict__ zpi,
    int8_t* __restrict__ xp2, int8_t* __restrict__ bp, int* __restrict__ BG)
{
    __shared__ int sm[1824];
    const int tid = threadIdx.x, bid = blockIdx.x;
    const int zp = *zpi;
    const int zp4 = (zp & 255) * 0x01010101;

    if (bid < HH * NB) {
        const int n = bid / HH, h = bid % HH;
        #pragma unroll
        for (int it = 0; it < 7; ++it) {
            int j = tid + it * 256;                 // 1792 = 128 ci x 14 w4
            int ci = j / 14, w4 = j - ci * 14;
            const v4i v = *(const v4i*)(x + ((n * CI + ci) * HH + h) * WW + w4 * 4);
            sm[w4 * 130 + ci] = (v.x & 255) | ((v.y & 255) << 8) |
                                ((v.z & 255) << 16) | (v.w << 24);
        }
        __syncthreads();
        int* od = (int*)xp2 + (n * HP + h + 1) * (WP * CI / 4);  // 2048 dwords
        #pragma unroll
        for (int it = 0; it < 8; ++it) {
            int j = tid + it * 256;                 // j = widx*32 + ci4
            int widx = j >> 5, ci4 = j & 31;
            int val = zp4;                          // pad value = zp
            if (widx >= 1 && widx <= WW) {
                int w = widx - 1;
                int base = (w >> 2) * 130 + ci4 * 4;
                int sh = (w & 3) * 8;
                val = ((sm[base] >> sh) & 0xff) | (((sm[base+1] >> sh) & 0xff) << 8) |
                      (((sm[base+2] >> sh) & 0xff) << 16) | ((sm[base+3] >> sh) << 24);
            }
            od[j ^ ((widx & 7) << 2)] = val;        // XOR-swizzle 16-B units
        }
    } else if (bid < HH * NB + 2 * NB) {
        const int z = bid - HH * NB;
        const int n = z >> 1, hidx = (z & 1) ? (HP - 1) : 0;
        int* od = (int*)xp2 + (n * HP + hidx) * (WP * CI / 4);
        #pragma unroll
        for (int it = 0; it < 8; ++it) od[tid + it * 256] = zp4;  // zp border rows
    } else {
        const int co = bid - (HH * NB + 2 * NB);
        for (int j = tid; j < 1152; j += 256) sm[j] = wgt[co * 1152 + j];  // [ci][9]
        __syncthreads();
        for (int j = tid; j < 288; j += 256) {      // 9t x 2c64 x 4q x 4j4
            int j4 = j & 3, q = (j >> 2) & 3, c64 = (j >> 4) & 1, t = j >> 5;
            int ci = c64 * 64 + q * 16 + j4 * 4;
            int b0 = sm[(ci + 0) * 9 + t] & 255, b1 = sm[(ci + 1) * 9 + t] & 255;
            int b2 = sm[(ci + 2) * 9 + t] & 255, b3 = sm[(ci + 3) * 9 + t];
            ((int*)bp)[((t * 2 + c64) * 4 + q) * 1024 + co * 4 + j4] =
                b0 | (b1 << 8) | (b2 << 16) | (b3 << 24);
        }
        if (tid < 9) {
            int s = 0;
            for (int ci = 0; ci < CI; ++ci) s += sm[ci * 9 + tid];
            sm[1152 + tid] = s;
        }
        __syncthreads();
        if (tid == 0) {
            int s9 = 0;
            for (int t = 0; t < 9; ++t) s9 += sm[1152 + t];
            BG[co] = bias[co] - zp * s9;            // cls-independent correction
        }
    }
}

// ---- main: 512 blocks x 256 thr, 2 blocks/CU; block = 112M x 128co ----
__global__ __launch_bounds__(256, 2) void qconv_mfma(
    const int8_t* __restrict__ xp2, const int8_t* __restrict__ bp,
    const int* __restrict__ BG,
    const float* __restrict__ si, const float* __restrict__ sw,
    const float* __restrict__ so, const int* __restrict__ zpo,
    int* __restrict__ out)
{
    const int tid  = threadIdx.x, lane = tid & 63, wid = tid >> 6;
    const int quad = lane >> 4, lo16 = lane & 15;
    const int bid  = blockIdx.x;                    // 512 blocks, 2 per CU
    const int xcd  = bid & 7, i = bid >> 3;         // i 0..63 within XCD
    // tiles per XCD: 224 = 4n x 2cb x 28s; this block's tiles t_j = i + 64*j
    const int n    = xcd * 4 + (i & 3);             // constant across j
    const int cb   = (i >> 2) & 1;                  // constant across j
    const int sA   = i >> 3;                        // s_j = sA + 8*j
    const int ntiles = (i < 32) ? 4 : 3;
    const int cw   = cb * 128 + wid * 32;           // wave co base (32 co)

    __shared__ __attribute__((aligned(16))) int8_t Asm[2][ABUF];  // 64 KB

    // ---- prologue: stage slab sA (4 padded rows, 32 KB) into buf0 ----
    const int8_t* src0 = xp2 + (((size_t)n * HP + 2 * sA) << 13);
    #pragma unroll
    for (int k = 0; k < 8; ++k) {
        const int u = wid + 4 * k;                  // 32 x 1-KB units
        __builtin_amdgcn_global_load_lds(
            (const __attribute__((address_space(1))) void*)(src0 + (u << 10) + lane * 16),
            (__attribute__((address_space(3))) void*)(&Asm[0][u << 10]), 16, 0, 0);
    }

    int bgv[2];
    #pragma unroll
    for (int ct = 0; ct < 2; ++ct) bgv[ct] = BG[cw + ct * 16 + lo16];
    const float rs = (*si) * (*sw) / (*so);
    const float zo = (float)(*zpo);

    // per-mt geometry (slab-local): base offset + packed swizzle per tap-col
    int boff[7], sw3[7];
    #pragma unroll
    for (int mt = 0; mt < 7; ++mt) {
        const int ml = mt * 16 + lo16;              // 0..111 within slab
        const int srow = ml / 56, scol = ml - srow * 56;
        boff[mt] = srow * 8192 + scol * 128 + quad * 16;
        int s0 = ((scol + 0) & 7) << 4, s1 = ((scol + 1) & 7) << 4,
            s2 = ((scol + 2) & 7) << 4;
        sw3[mt] = s0 | (s1 << 8) | (s2 << 16);      // swizzle per dc, packed
    }

    // B stream base for this wave: page (t*8 + c64*4 + quad), entry (co)*16
    const int8_t* bwav = bp + ((size_t)quad << 12) + ((cw + lo16) << 4);

    int* optr0 = out + ((size_t)n * CO + cw + lo16) * SPA + quad * 4;
    int* optr1 = optr0 + 16 * SPA;

    __syncthreads();                                // prologue drained (vmcnt(0) ok here)

    // issue B fragments for tap tp (laundered base: blocks LICM hoisting)
    #define BLOAD(tp) {                                                        \
        const int8_t* bb = bwav + ((tp) * 8 << 12);                            \
        asm volatile("" : "+v"(bb));                                           \
        bt[tp][0] = *(const v4i*)(bb);                                         \
        bt[tp][1] = *(const v4i*)(bb + 256);                                   \
        bt[tp][2] = *(const v4i*)(bb + 16384);                                 \
        bt[tp][3] = *(const v4i*)(bb + 16384 + 256);                           \
    }

    #pragma unroll 1
    for (int j = 0; j < ntiles; ++j) {
        const int s = sA + 8 * j;                   // slab 0..27
        const int8_t* curA = Asm[j & 1];

        v4i bt[9][4];                               // streamed B (short-lived)
        BLOAD(0); BLOAD(1);                         // before A-stage: consuming
                                                    // them never drains A loads

        // ---- issue async stage of slab s+8 into the idle buffer ----
        if (j + 1 < ntiles) {
            const int8_t* srcn = xp2 + (((size_t)n * HP + 2 * (s + 8)) << 13);
            int8_t* dst = (int8_t*)Asm[(j & 1) ^ 1];
            #pragma unroll
            for (int k = 0; k < 8; ++k) {
                const int u = wid + 4 * k;
                __builtin_amdgcn_global_load_lds(
                    (const __attribute__((address_space(1))) void*)(srcn + (u << 10) + lane * 16),
                    (__attribute__((address_space(3))) void*)(dst + (u << 10)), 16, 0, 0);
            }
        }
        __builtin_amdgcn_sched_barrier(0);          // pin load issue before K-loop

        v4i acc[7][2];
        #pragma unroll
        for (int mt = 0; mt < 7; ++mt) {
            acc[mt][0] = (v4i){0, 0, 0, 0};
            acc[mt][1] = (v4i){0, 0, 0, 0};
        }

        // ---- K-loop: 9 taps x 7 mt x (2 LDS reads + 4 MFMA); B streamed
        //      2 taps ahead from L2 ----
        __builtin_amdgcn_s_setprio(1);
        #pragma unroll
        for (int tp = 0; tp < 9; ++tp) {
            if (tp + 2 <= 8) BLOAD(tp + 2);
            const int dr = tp / 3, dc = tp % 3;
            #pragma unroll
            for (int mt = 0; mt < 7; ++mt) {
                const int off  = boff[mt] + dr * 8192 + dc * 128;
                const int phys = off ^ ((sw3[mt] >> (8 * dc)) & 0x70);
                v4i a0 = *(const v4i*)(curA + phys);          // logical ci 0..63
                v4i a1 = *(const v4i*)(curA + (phys ^ 64));   // logical +64 -> phys^64
                acc[mt][0] = __builtin_amdgcn_mfma_i32_16x16x64_i8(a0, bt[tp][0], acc[mt][0], 0, 0, 0);
                acc[mt][1] = __builtin_amdgcn_mfma_i32_16x16x64_i8(a0, bt[tp][1], acc[mt][1], 0, 0, 0);
                acc[mt][0] = __builtin_amdgcn_mfma_i32_16x16x64_i8(a1, bt[tp][2], acc[mt][0], 0, 0, 0);
                acc[mt][1] = __builtin_amdgcn_mfma_i32_16x16x64_i8(a1, bt[tp][3], acc[mt][1], 0, 0, 0);
            }
        }
        __builtin_amdgcn_s_setprio(0);

        // ---- epilogue: requant + 14 direct v4i stores (after the 8 loads) ----
        const int m0 = s * 112;
        #pragma unroll
        for (int mt = 0; mt < 7; ++mt) {
            v4i v0, v1;
            #pragma unroll
            for (int i4 = 0; i4 < 4; ++i4) {        // C/D row = quad*4+i4
                float y0 = rintf((float)(acc[mt][0][i4] + bgv[0]) * rs + zo);
                float y1 = rintf((float)(acc[mt][1][i4] + bgv[1]) * rs + zo);
                v0[i4] = (int)fminf(fmaxf(y0, -128.f), 127.f);
                v1[i4] = (int)fminf(fmaxf(y1, -128.f), 127.f);
            }
            *(v4i*)(optr0 + m0 + mt * 16) = v0;
            *(v4i*)(optr1 + m0 + mt * 16) = v1;
        }

        // ---- release: wait for the 8 stage loads (14 newest = stores stay
        //      in flight; B loads all consumed), then barrier. ----
        if (j + 1 < ntiles) {
            __builtin_amdgcn_sched_barrier(0);
            asm volatile("s_waitcnt vmcnt(14)" ::: "memory");
            __builtin_amdgcn_s_barrier();
            __builtin_amdgcn_sched_barrier(0);
        }
    }
    #undef BLOAD
}

extern "C" void kernel_launch(void* const* d_in, const int* in_sizes, int n_in,
                              void* d_out, int out_size, void* d_ws, size_t ws_size,
                              hipStream_t stream) {
    const int*   x    = (const int*)d_in[0];
    const int*   wgt  = (const int*)d_in[1];
    const int*   bias = (const int*)d_in[2];
    const float* si   = (const float*)d_in[3];
    const float* sw   = (const float*)d_in[4];
    const float* so   = (const float*)d_in[5];
    const int*   zpi  = (const int*)d_in[6];
    const int*   zpo  = (const int*)d_in[7];
    int* out = (int*)d_out;

    int8_t* xp2 = (int8_t*)d_ws;
    int8_t* bp  = xp2 + XP2_BYTES;
    int*    bg  = (int*)(bp + BP_BYTES);

    prep_kernel<<<HH * NB + 2 * NB + CO, 256, 0, stream>>>(x, wgt, bias, zpi, xp2, bp, bg);
    qconv_mfma<<<512, 256, 0, stream>>>(xp2, bp, bg, si, sw, so, zpo, out);
}